// Round 2
// baseline (1088.409 us; speedup 1.0000x reference)
//
#include <hip/hip_runtime.h>
#include <hip/hip_bf16.h>

typedef _Float16 half8 __attribute__((ext_vector_type(8)));
typedef float    f32x4 __attribute__((ext_vector_type(4)));

// ---------------- cast Wk|Wq|Wv (fp32 [1024][64] each) -> fp16 concat [1024][192] ----------------
__global__ __launch_bounds__(256) void cast_w(const float* __restrict__ Wk,
                                              const float* __restrict__ Wq,
                                              const float* __restrict__ Wv,
                                              _Float16* __restrict__ wcat) {
    int tid = blockIdx.x * 256 + threadIdx.x;
    if (tid >= 1024 * 192) return;
    int row = tid / 192, c = tid % 192;
    float v;
    if (c < 64)       v = Wk[row * 64 + c];
    else if (c < 128) v = Wq[row * 64 + (c - 64)];
    else              v = Wv[row * 64 + (c - 128)];
    wcat[tid] = (_Float16)v;
}

// ---------------- qkv = x @ wcat : M=131072, K=1024, N=192, fp32 out ----------------
#define BM 64
#define BN 64
#define BK 32
#define LDA 40   // padded leading dim (halfs) for bank spread + 16B alignment
#define LDB 40

__global__ __launch_bounds__(256) void qkv_gemm(const float* __restrict__ x,
                                                const _Float16* __restrict__ w,  // [1024][192]
                                                float* __restrict__ qkv) {
    __shared__ __align__(16) _Float16 As[BM * LDA];   // A tile, [m][k]
    __shared__ __align__(16) _Float16 Bt[BN * LDB];   // B tile transposed, [n][k]

    const int tid   = threadIdx.x;
    const int m0    = blockIdx.x * BM;
    const int n0    = blockIdx.y * BN;
    const int wave  = tid >> 6;
    const int lane  = tid & 63;
    const int wm    = (wave & 1) * 32;
    const int wn    = (wave >> 1) * 32;
    const int lrow  = lane & 15;
    const int lq    = lane >> 4;

    f32x4 acc[2][2] = {};

    // staging maps
    const int ar = tid >> 2;            // 0..63  (A row)
    const int ac = (tid & 3) * 8;       // 0,8,16,24 (A col)
    const int br = tid >> 3;            // 0..31  (B k-row)
    const int bc = (tid & 7) * 8;       // 0..56  (B n-col)

    const float*    xg = x + (size_t)(m0 + ar) * 1024 + ac;
    const _Float16* wg = w + (size_t)br * 192 + n0 + bc;

    for (int kb = 0; kb < 1024; kb += BK) {
        // ---- stage A (fp32 -> fp16) ----
        float4 a0 = *(const float4*)(xg + kb);
        float4 a1 = *(const float4*)(xg + kb + 4);
        half8 av;
        av[0] = (_Float16)a0.x; av[1] = (_Float16)a0.y; av[2] = (_Float16)a0.z; av[3] = (_Float16)a0.w;
        av[4] = (_Float16)a1.x; av[5] = (_Float16)a1.y; av[6] = (_Float16)a1.z; av[7] = (_Float16)a1.w;
        *(half8*)&As[ar * LDA + ac] = av;
        // ---- stage B transposed ----
        half8 bv = *(const half8*)(wg + (size_t)kb * 192);
        #pragma unroll
        for (int i = 0; i < 8; ++i) Bt[(bc + i) * LDB + br] = bv[i];

        __syncthreads();

        half8 aF0 = *(const half8*)&As[(wm + lrow) * LDA + lq * 8];
        half8 aF1 = *(const half8*)&As[(wm + 16 + lrow) * LDA + lq * 8];
        half8 bF0 = *(const half8*)&Bt[(wn + lrow) * LDB + lq * 8];
        half8 bF1 = *(const half8*)&Bt[(wn + 16 + lrow) * LDB + lq * 8];

        acc[0][0] = __builtin_amdgcn_mfma_f32_16x16x32_f16(aF0, bF0, acc[0][0], 0, 0, 0);
        acc[0][1] = __builtin_amdgcn_mfma_f32_16x16x32_f16(aF0, bF1, acc[0][1], 0, 0, 0);
        acc[1][0] = __builtin_amdgcn_mfma_f32_16x16x32_f16(aF1, bF0, acc[1][0], 0, 0, 0);
        acc[1][1] = __builtin_amdgcn_mfma_f32_16x16x32_f16(aF1, bF1, acc[1][1], 0, 0, 0);

        __syncthreads();
    }

    // epilogue: D[row=(lane>>4)*4+r][col=lane&15]
    #pragma unroll
    for (int mi = 0; mi < 2; ++mi)
        #pragma unroll
        for (int ni = 0; ni < 2; ++ni)
            #pragma unroll
            for (int r = 0; r < 4; ++r) {
                int row = m0 + wm + mi * 16 + lq * 4 + r;
                int col = n0 + wn + ni * 16 + lrow;
                qkv[(size_t)row * 192 + col] = acc[mi][ni][r];
            }
}

// ---------------- causal attention, one block per batch ----------------
// qkv layout per row [192]: k = cols 0..63, q = 64..127, v = 128..191
__global__ __launch_bounds__(128) void attn(const float* __restrict__ qkv,
                                            float* __restrict__ out) {
    __shared__ float ks[128 * 64];
    __shared__ float vs[128 * 64];
    const int b = blockIdx.x;
    const int t = threadIdx.x;
    const size_t base = (size_t)b * 128;

    // coalesced load of k,v into LDS: 2048 float4 each
    #pragma unroll
    for (int i = 0; i < 16; ++i) {
        int idx = i * 128 + t;          // 0..2047
        int row = idx >> 4, col = idx & 15;
        ((float4*)ks)[idx] = *(const float4*)(qkv + (base + row) * 192 + col * 4);
        ((float4*)vs)[idx] = *(const float4*)(qkv + (base + row) * 192 + 128 + col * 4);
    }
    // q row for this thread
    float4 q4[16];
    #pragma unroll
    for (int i = 0; i < 16; ++i)
        q4[i] = *(const float4*)(qkv + (base + t) * 192 + 64 + i * 4);
    __syncthreads();

    float m = -INFINITY, l = 0.f;
    float4 o4[16];
    #pragma unroll
    for (int i = 0; i < 16; ++i) { o4[i].x = 0.f; o4[i].y = 0.f; o4[i].z = 0.f; o4[i].w = 0.f; }

    for (int j = 0; j <= t; ++j) {
        const float4* kr = (const float4*)(ks + j * 64);
        float s = 0.f;
        #pragma unroll
        for (int i = 0; i < 16; ++i) {
            float4 kv = kr[i];
            s = fmaf(q4[i].x, kv.x, s); s = fmaf(q4[i].y, kv.y, s);
            s = fmaf(q4[i].z, kv.z, s); s = fmaf(q4[i].w, kv.w, s);
        }
        float mn = fmaxf(m, s);
        float c  = __expf(m - mn);
        float p  = __expf(s - mn);
        l = l * c + p;
        const float4* vr = (const float4*)(vs + j * 64);
        #pragma unroll
        for (int i = 0; i < 16; ++i) {
            float4 vv = vr[i];
            o4[i].x = fmaf(p, vv.x, o4[i].x * c);
            o4[i].y = fmaf(p, vv.y, o4[i].y * c);
            o4[i].z = fmaf(p, vv.z, o4[i].z * c);
            o4[i].w = fmaf(p, vv.w, o4[i].w * c);
        }
        m = mn;
    }
    float inv = 1.f / l;
    #pragma unroll
    for (int i = 0; i < 16; ++i) {
        float4 r;
        r.x = o4[i].x * inv; r.y = o4[i].y * inv; r.z = o4[i].z * inv; r.w = o4[i].w * inv;
        *(float4*)(out + (base + t) * 64 + i * 4) = r;
    }
}

extern "C" void kernel_launch(void* const* d_in, const int* in_sizes, int n_in,
                              void* d_out, int out_size, void* d_ws, size_t ws_size,
                              hipStream_t stream) {
    const float* x  = (const float*)d_in[0];
    const float* Wk = (const float*)d_in[1];
    const float* Wq = (const float*)d_in[2];
    const float* Wv = (const float*)d_in[3];
    float* out = (float*)d_out;

    _Float16* wcat = (_Float16*)d_ws;                                 // 1024*192*2 = 384 KB
    float*    qkv  = (float*)((char*)d_ws + (size_t)1024 * 192 * 2);  // 131072*192*4 = 100.7 MB

    cast_w<<<768, 256, 0, stream>>>(Wk, Wq, Wv, wcat);
    qkv_gemm<<<dim3(2048, 3), 256, 0, stream>>>(x, wcat, qkv);
    attn<<<1024, 128, 0, stream>>>(qkv, out);
}

// Round 3
// 865.253 us; speedup vs baseline: 1.2579x; 1.2579x over previous
//
#include <hip/hip_runtime.h>
#include <hip/hip_bf16.h>

typedef _Float16 half2_t __attribute__((ext_vector_type(2)));
typedef _Float16 half4_t __attribute__((ext_vector_type(4)));
typedef _Float16 half8_t __attribute__((ext_vector_type(8)));
typedef float    f32x4   __attribute__((ext_vector_type(4)));

static __device__ __forceinline__ half2_t pk2(float a, float b) {
#if __has_builtin(__builtin_amdgcn_cvt_pkrtz)
    auto r = __builtin_amdgcn_cvt_pkrtz(a, b);
    half2_t h; h[0] = (_Float16)r[0]; h[1] = (_Float16)r[1]; return h;
#else
    half2_t h; h[0] = (_Float16)a; h[1] = (_Float16)b; return h;
#endif
}

#if __has_builtin(__builtin_amdgcn_fdot2)
#define FDOT2(a, b, c) __builtin_amdgcn_fdot2((a), (b), (c), false)
#else
#define FDOT2(a, b, c) fmaf((float)(a)[0], (float)(b)[0], fmaf((float)(a)[1], (float)(b)[1], (c)))
#endif

// ---------------- cast + transpose: Wk|Wq|Wv fp32 [1024][64] -> wT fp16 [192][1024] ----------------
__global__ __launch_bounds__(256) void cast_wT(const float* __restrict__ Wk,
                                               const float* __restrict__ Wq,
                                               const float* __restrict__ Wv,
                                               _Float16* __restrict__ wT) {
    int idx = blockIdx.x * 256 + threadIdx.x;       // 192*1024
    int c = idx & 1023, n = idx >> 10;
    float v;
    if (n < 64)       v = Wk[c * 64 + n];
    else if (n < 128) v = Wq[c * 64 + (n - 64)];
    else              v = Wv[c * 64 + (n - 128)];
    wT[idx] = (_Float16)v;
}

// ---------------- qkv = x @ W : M=131072, K=1024, N=192 (full N per block) ----------------
#define LDA 40
#define LDB 40

__global__ __launch_bounds__(256, 3) void qkv_gemm(const float* __restrict__ x,
                                                   const _Float16* __restrict__ wT,  // [192][1024]
                                                   float* __restrict__ qkv) {
    __shared__ __align__(16) _Float16 As[128 * LDA];   // [m][k], k=32
    __shared__ __align__(16) _Float16 Bt[192 * LDB];   // [n][k]

    const int tid  = threadIdx.x;
    const int m0   = blockIdx.x * 128;
    const int wave = tid >> 6;
    const int lane = tid & 63;
    const int wm   = wave * 32;
    const int lrow = lane & 15;
    const int lq   = lane >> 4;

    f32x4 acc[2][12] = {};

    // staging maps
    const int arow = tid >> 3;          // 0..31 (+p*32)
    const int acol = (tid & 7) * 4;     // float/half k-offset, 0..28
    const int brow = tid >> 2;          // 0..63 (+p*64)
    const int bcol = (tid & 3) * 8;     // half k-offset, 0..24

    const float*    xg = x  + (size_t)(m0 + arow) * 1024 + acol;
    const _Float16* wg = wT + (size_t)brow * 1024 + bcol;

    for (int kb = 0; kb < 1024; kb += 32) {
        // ---- stage A: 128 rows x 32 halfs ----
        #pragma unroll
        for (int p = 0; p < 4; ++p) {
            float4 a = *(const float4*)(xg + (size_t)p * 32 * 1024 + kb);
            half2_t h0 = pk2(a.x, a.y), h1 = pk2(a.z, a.w);
            half4_t hv = {h0[0], h0[1], h1[0], h1[1]};
            *(half4_t*)&As[(arow + p * 32) * LDA + acol] = hv;
        }
        // ---- stage B: 192 rows x 32 halfs (straight copy, wT already transposed) ----
        #pragma unroll
        for (int p = 0; p < 3; ++p) {
            half8_t bv = *(const half8_t*)(wg + (size_t)p * 64 * 1024 + kb);
            *(half8_t*)&Bt[(brow + p * 64) * LDB + bcol] = bv;
        }
        __syncthreads();

        half8_t aF0 = *(const half8_t*)&As[(wm + lrow) * LDA + lq * 8];
        half8_t aF1 = *(const half8_t*)&As[(wm + 16 + lrow) * LDA + lq * 8];
        #pragma unroll
        for (int nt = 0; nt < 12; ++nt) {
            half8_t bF = *(const half8_t*)&Bt[(nt * 16 + lrow) * LDB + lq * 8];
            acc[0][nt] = __builtin_amdgcn_mfma_f32_16x16x32_f16(aF0, bF, acc[0][nt], 0, 0, 0);
            acc[1][nt] = __builtin_amdgcn_mfma_f32_16x16x32_f16(aF1, bF, acc[1][nt], 0, 0, 0);
        }
        __syncthreads();
    }

    // epilogue: D[row=lq*4+r][col=lrow]
    #pragma unroll
    for (int mt = 0; mt < 2; ++mt)
        #pragma unroll
        for (int nt = 0; nt < 12; ++nt)
            #pragma unroll
            for (int r = 0; r < 4; ++r) {
                int row = m0 + wm + mt * 16 + lq * 4 + r;
                int col = nt * 16 + lrow;
                qkv[(size_t)row * 192 + col] = acc[mt][nt][r];
            }
}

// ---------------- causal attention, one block (256 thr) per batch ----------------
// qkv row layout [192]: k = 0..63, q = 64..127, v = 128..191
__global__ __launch_bounds__(256) void attn(const float* __restrict__ qkv,
                                            float* __restrict__ out) {
    __shared__ __align__(16) _Float16 ks[128 * 72];   // k rows [j][h], padded
    __shared__ __align__(16) _Float16 vT[64 * 136];   // v transposed [h][j], padded
    __shared__ _Float16 ps16[4][128];                 // per-wave normalized probs

    const int b = blockIdx.x, t = threadIdx.x;
    const size_t base = (size_t)b * 128;

    // ---- stage k (row-major fp16) and v (transposed fp16) ----
    {
        int j = t >> 1, h0 = (t & 1) * 32;
        const float4* krow = (const float4*)(qkv + (base + j) * 192 + h0);
        const float4* vrow = (const float4*)(qkv + (base + j) * 192 + 128 + h0);
        #pragma unroll
        for (int i = 0; i < 8; ++i) {
            float4 kv = krow[i];
            half2_t a = pk2(kv.x, kv.y), c = pk2(kv.z, kv.w);
            half4_t hv = {a[0], a[1], c[0], c[1]};
            *(half4_t*)&ks[j * 72 + h0 + i * 4] = hv;
            float4 vv = vrow[i];
            vT[(h0 + i * 4 + 0) * 136 + j] = (_Float16)vv.x;
            vT[(h0 + i * 4 + 1) * 136 + j] = (_Float16)vv.y;
            vT[(h0 + i * 4 + 2) * 136 + j] = (_Float16)vv.z;
            vT[(h0 + i * 4 + 3) * 136 + j] = (_Float16)vv.w;
        }
    }
    __syncthreads();

    const int wave = t >> 6, lane = t & 63;
    const half8_t* k0p = (const half8_t*)&ks[lane * 72];
    const half8_t* k1p = (const half8_t*)&ks[(64 + lane) * 72];
    const half8_t* vp  = (const half8_t*)&vT[lane * 136];

    for (int rr = 0; rr < 32; ++rr) {
        const int row = rr * 4 + wave;                 // wave-uniform
        const float4* qg = (const float4*)(qkv + (base + row) * 192 + 64);

        // ---- phase 1: scores for keys lane (and 64+lane) ----
        float s0 = 0.f, s1 = -INFINITY;
        {
            float s0a = 0.f, s0b = 0.f;
            if (row >= 64) {
                float s1a = 0.f, s1b = 0.f;
                #pragma unroll
                for (int i = 0; i < 8; ++i) {
                    float4 qA = qg[2 * i], qB = qg[2 * i + 1];
                    half2_t q0 = pk2(qA.x, qA.y), q1 = pk2(qA.z, qA.w);
                    half2_t q2 = pk2(qB.x, qB.y), q3 = pk2(qB.z, qB.w);
                    half8_t ka = k0p[i], kb = k1p[i];
                    half2_t c0 = {ka[0], ka[1]}, c1 = {ka[2], ka[3]}, c2 = {ka[4], ka[5]}, c3 = {ka[6], ka[7]};
                    half2_t d0 = {kb[0], kb[1]}, d1 = {kb[2], kb[3]}, d2 = {kb[4], kb[5]}, d3 = {kb[6], kb[7]};
                    s0a = FDOT2(q0, c0, s0a); s0b = FDOT2(q1, c1, s0b);
                    s0a = FDOT2(q2, c2, s0a); s0b = FDOT2(q3, c3, s0b);
                    s1a = FDOT2(q0, d0, s1a); s1b = FDOT2(q1, d1, s1b);
                    s1a = FDOT2(q2, d2, s1a); s1b = FDOT2(q3, d3, s1b);
                }
                s0 = s0a + s0b;
                s1 = (64 + lane <= row) ? (s1a + s1b) : -INFINITY;
            } else {
                #pragma unroll
                for (int i = 0; i < 8; ++i) {
                    float4 qA = qg[2 * i], qB = qg[2 * i + 1];
                    half2_t q0 = pk2(qA.x, qA.y), q1 = pk2(qA.z, qA.w);
                    half2_t q2 = pk2(qB.x, qB.y), q3 = pk2(qB.z, qB.w);
                    half8_t ka = k0p[i];
                    half2_t c0 = {ka[0], ka[1]}, c1 = {ka[2], ka[3]}, c2 = {ka[4], ka[5]}, c3 = {ka[6], ka[7]};
                    s0a = FDOT2(q0, c0, s0a); s0b = FDOT2(q1, c1, s0b);
                    s0a = FDOT2(q2, c2, s0a); s0b = FDOT2(q3, c3, s0b);
                }
                s0 = (lane <= row) ? (s0a + s0b) : -INFINITY;
            }
        }
        // ---- softmax across the wave ----
        float m = fmaxf(s0, s1);
        #pragma unroll
        for (int d = 1; d < 64; d <<= 1) m = fmaxf(m, __shfl_xor(m, d, 64));
        float p0 = __expf(s0 - m), p1 = __expf(s1 - m);
        float l = p0 + p1;
        #pragma unroll
        for (int d = 1; d < 64; d <<= 1) l += __shfl_xor(l, d, 64);
        float inv = 1.f / l;
        ps16[wave][lane]      = (_Float16)(p0 * inv);
        ps16[wave][64 + lane] = (_Float16)(p1 * inv);

        // ---- phase 2: out[h=lane] = sum_j p[j] * v[j][h] ----
        const int nj = row + 1;
        float o0 = 0.f, o1 = 0.f, o2 = 0.f, o3 = 0.f;
        const int n8 = nj >> 3;
        for (int i = 0; i < n8; ++i) {
            half8_t pv = *(const half8_t*)&ps16[wave][i * 8];   // broadcast
            half8_t vv = vp[i];
            half2_t pa = {pv[0], pv[1]}, pb = {pv[2], pv[3]}, pc = {pv[4], pv[5]}, pd = {pv[6], pv[7]};
            half2_t va = {vv[0], vv[1]}, vb = {vv[2], vv[3]}, vc = {vv[4], vv[5]}, vd = {vv[6], vv[7]};
            o0 = FDOT2(pa, va, o0); o1 = FDOT2(pb, vb, o1);
            o2 = FDOT2(pc, vc, o2); o3 = FDOT2(pd, vd, o3);
        }
        for (int j = n8 * 8; j < nj; ++j)
            o0 = fmaf((float)ps16[wave][j], (float)vT[lane * 136 + j], o0);

        out[(base + row) * 64 + lane] = (o0 + o1) + (o2 + o3);
    }
}

extern "C" void kernel_launch(void* const* d_in, const int* in_sizes, int n_in,
                              void* d_out, int out_size, void* d_ws, size_t ws_size,
                              hipStream_t stream) {
    const float* x  = (const float*)d_in[0];
    const float* Wk = (const float*)d_in[1];
    const float* Wq = (const float*)d_in[2];
    const float* Wv = (const float*)d_in[3];
    float* out = (float*)d_out;

    _Float16* wT  = (_Float16*)d_ws;                                  // 192*1024*2 = 384 KB
    float*    qkv = (float*)((char*)d_ws + (size_t)192 * 1024 * 2);   // 131072*192*4 = 100.7 MB

    cast_wT<<<768, 256, 0, stream>>>(Wk, Wq, Wv, wT);
    qkv_gemm<<<1024, 256, 0, stream>>>(x, wT, qkv);
    attn<<<1024, 256, 0, stream>>>(qkv, out);
}